// Round 10
// baseline (258.457 us; speedup 1.0000x reference)
//
#include <hip/hip_runtime.h>
#include <math.h>

#define N_NODES 20000
#define N_EDGES 320000
#define ET (N_EDGES + N_NODES)   // edges + self loops
#define IN_CH 256
#define HID 128
#define HEADS 4
#define OUT_CH 16
#define N_GRAPHS 128
#define NEG_SLOPE 0.2f
#define LOG2E 1.44269504f

typedef _Float16 f16x8 __attribute__((ext_vector_type(8)));
typedef _Float16 f16x4 __attribute__((ext_vector_type(4)));
typedef _Float16 f16x2 __attribute__((ext_vector_type(2)));
typedef float f32x4 __attribute__((ext_vector_type(4)));
typedef float f32x2 __attribute__((ext_vector_type(2)));

#define LDT 40   // padded LDS stride in f16 (80 B: 16B-aligned, 2-way max conflict)

// ========== K1: prep (W transpose, att folds, goff) + edge histogram ========
// cnt must be zeroed beforehand (hipMemsetAsync).
#define P1 (IN_CH * HEADS * HID)   // W1T
#define P2 (HEADS * HID * HID)     // W2T
#define P3 (8 * IN_CH)             // wt1 (pre-scaled by LOG2E)
#define P4 (HEADS * HID)           // wt2 (pre-scaled by LOG2E)
#define P5 (N_GRAPHS + 1)          // goff (binary search over sorted batch)
#define P6 ET                      // histogram by dst (incl self loops)
#define PH_TOTAL (P1 + P2 + P3 + P4 + P5 + P6)
__global__ void prep_hist(const float* __restrict__ W1, const float* __restrict__ W2,
    const float* __restrict__ as1, const float* __restrict__ ad1,
    const float* __restrict__ as2, const float* __restrict__ ad2,
    const int* __restrict__ batch, const int* __restrict__ dst,
    int* __restrict__ cnt,
    _Float16* __restrict__ W1T, _Float16* __restrict__ W2T,
    float* __restrict__ wt1, float* __restrict__ wt2, int* __restrict__ goff) {
  int idx = blockIdx.x * blockDim.x + threadIdx.x;
  if (idx < P1) {  // W1T[n*256+k] = W1[k*512+n]
    int n = idx >> 8, k = idx & 255;
    W1T[idx] = (_Float16)W1[(size_t)k * (HEADS * HID) + n];
    return;
  }
  idx -= P1;
  if (idx < P2) {  // W2T[n*512+k] = W2[k*128+n]
    int n = idx >> 9, k = idx & 511;
    W2T[idx] = (_Float16)W2[(size_t)k * HID + n];
    return;
  }
  idx -= P2;
  if (idx < P3) {  // wt1[j][i] = LOG2E * sum_c W1[i, h*128+c] * a{s,d}1[h][c]
    int j = idx >> 8, i = idx & 255;
    int sd = j >> 2, h = j & 3;
    const float* av = sd ? ad1 : as1;
    float s = 0.f;
    for (int c = 0; c < HID; ++c)
      s += W1[(size_t)i * (HEADS * HID) + h * HID + c] * av[h * HID + c];
    wt1[idx] = s * LOG2E;
    return;
  }
  idx -= P3;
  if (idx < P4) {  // wt2[0][c], wt2[1][c] (scaled by LOG2E)
    float s = 0.f, d = 0.f;
    for (int j = 0; j < HID; ++j) {
      float w = W2[(size_t)idx * HID + j];
      s += w * as2[j];
      d += w * ad2[j];
    }
    wt2[idx] = s * LOG2E;
    wt2[HEADS * HID + idx] = d * LOG2E;
    return;
  }
  idx -= P4;
  if (idx < P5) {  // batch sorted: goff[g] = lower_bound(batch, g)
    int g = idx;
    int lo = 0, hi = N_NODES;
    while (lo < hi) {
      int mid = (lo + hi) >> 1;
      if (batch[mid] < g) lo = mid + 1; else hi = mid;
    }
    goff[g] = lo;
    return;
  }
  idx -= P5;
  if (idx < P6) {  // histogram
    int d = (idx < N_EDGES) ? dst[idx] : (idx - N_EDGES);
    atomicAdd(&cnt[d], 1);
  }
}

// ===== K2: conv_x (blocks 0..4999) + exclusive scan (block 5000) ===========
#define SCB 5000   // conv blocks; block SCB runs the scan
__global__ __launch_bounds__(256) void conv_scan(const float* __restrict__ x,
    const float* __restrict__ wt1, _Float16* __restrict__ xb,
    float* __restrict__ a1s, float* __restrict__ a1d,
    const int* __restrict__ cnt, int* __restrict__ offs, int* __restrict__ cursor) {
  __shared__ int wsum[4];
  if (blockIdx.x == SCB) {
    int tid = threadIdx.x;
    int base = tid * 80;                 // 256*80 = 20480; N_NODES = 250*80
    int s = 0;
    if (base < N_NODES) {                // threads 0..249 fully in-range
      #pragma unroll
      for (int ch = 0; ch < 5; ch++) {
        int4 v[4];
        #pragma unroll
        for (int u = 0; u < 4; u++)
          v[u] = *(const int4*)(cnt + base + ch * 16 + u * 4);
        #pragma unroll
        for (int u = 0; u < 4; u++)
          s += v[u].x + v[u].y + v[u].z + v[u].w;
      }
    }
    int lane = tid & 63, w = tid >> 6;
    int xv = s;
    #pragma unroll
    for (int o = 1; o < 64; o <<= 1) {
      int t = __shfl_up(xv, o);
      if (lane >= o) xv += t;
    }
    if (lane == 63) wsum[w] = xv;
    __syncthreads();
    int carry = 0;
    #pragma unroll
    for (int i = 0; i < 4; i++) carry += (i < w) ? wsum[i] : 0;
    int total = wsum[0] + wsum[1] + wsum[2] + wsum[3];
    int run = carry + xv - s;            // exclusive prefix for this thread
    if (base < N_NODES) {
      #pragma unroll
      for (int ch = 0; ch < 5; ch++) {
        int4 v[4];
        #pragma unroll
        for (int u = 0; u < 4; u++)
          v[u] = *(const int4*)(cnt + base + ch * 16 + u * 4);   // L1-hot
        #pragma unroll
        for (int u = 0; u < 4; u++) {
          int4 o4;
          o4.x = run; run += v[u].x;
          o4.y = run; run += v[u].y;
          o4.z = run; run += v[u].z;
          o4.w = run; run += v[u].w;
          *(int4*)(offs + base + ch * 16 + u * 4) = o4;
          *(int4*)(cursor + base + ch * 16 + u * 4) = o4;
        }
      }
    }
    if (tid == 0) offs[N_NODES] = total;
    return;
  }
  int node = blockIdx.x * 4 + (threadIdx.x >> 6);
  int lane = threadIdx.x & 63;
  if (node >= N_NODES) return;
  int c = lane * 4;
  float4 xv = *(const float4*)(x + (size_t)node * IN_CH + c);
  *(f16x4*)(xb + (size_t)node * IN_CH + c) =
      f16x4{(_Float16)xv.x, (_Float16)xv.y, (_Float16)xv.z, (_Float16)xv.w};
  float p[8];
  #pragma unroll
  for (int jj = 0; jj < 8; ++jj) {
    float4 w = *(const float4*)(wt1 + jj * IN_CH + c);
    p[jj] = xv.x * w.x + xv.y * w.y + xv.z * w.z + xv.w * w.w;
  }
  #pragma unroll
  for (int o = 32; o > 0; o >>= 1)
    #pragma unroll
    for (int jj = 0; jj < 8; ++jj) p[jj] += __shfl_down(p[jj], o);
  if (lane == 0) {
    #pragma unroll
    for (int h = 0; h < 4; ++h) {
      a1s[node * HEADS + h] = p[h];
      a1d[node * HEADS + h] = p[4 + h];
    }
  }
}

// ===== K3: CSR fill (blocks 0..1328) + layer-1 MFMA GEMM (fp8 out) =========
#define FILL_BLOCKS ((ET + 255) / 256)          // 1329
#define G1_BN ((HEADS * HID) / 128)             // 4
#define G1_BM ((N_NODES + 127) / 128)           // 157
__global__ __launch_bounds__(256) void gemm1_fill(const _Float16* __restrict__ A,
    const _Float16* __restrict__ Bt, unsigned char* __restrict__ Cq,
    const int* __restrict__ src, const int* __restrict__ dst,
    int* __restrict__ cursor, int* __restrict__ csr) {
  __shared__ _Float16 As[128 * LDT];
  __shared__ _Float16 Bs[128 * LDT];
  if (blockIdx.x < FILL_BLOCKS) {
    int e = blockIdx.x * 256 + threadIdx.x;
    if (e >= ET) return;
    int s, d;
    if (e < N_EDGES) { s = src[e]; d = dst[e]; } else { s = d = e - N_EDGES; }
    int pos = atomicAdd(&cursor[d], 1);
    csr[pos] = s;
    return;
  }
  const int g = blockIdx.x - FILL_BLOCKS;
  const int bm = (g >> 2) * 128, bn = (g & 3) * 128;
  const int M = N_NODES, N = HEADS * HID, K = IN_CH;
  const int tid = threadIdx.x;
  const int lane = tid & 63, wv = tid >> 6;
  const int wr = wv >> 1, wc = wv & 1;
  const int r0 = tid >> 2, seg = tid & 3;
  const int m_lo = lane & 15, koff = (lane >> 4) * 8, rq = lane >> 4;
  f32x4 acc[4][4] = {};
  for (int k0 = 0; k0 < K; k0 += 32) {
    const int4 zero4 = {0, 0, 0, 0};
    int gr0 = bm + r0, gr1 = bm + r0 + 64;
    int4 av0 = (gr0 < M) ? *(const int4*)(A + (size_t)gr0 * K + k0 + seg * 8) : zero4;
    int4 av1 = (gr1 < M) ? *(const int4*)(A + (size_t)gr1 * K + k0 + seg * 8) : zero4;
    int4 bv0 = *(const int4*)(Bt + (size_t)(bn + r0) * K + k0 + seg * 8);
    int4 bv1 = *(const int4*)(Bt + (size_t)(bn + r0 + 64) * K + k0 + seg * 8);
    __syncthreads();
    *(int4*)(As + r0 * LDT + seg * 8) = av0;
    *(int4*)(As + (r0 + 64) * LDT + seg * 8) = av1;
    *(int4*)(Bs + r0 * LDT + seg * 8) = bv0;
    *(int4*)(Bs + (r0 + 64) * LDT + seg * 8) = bv1;
    __syncthreads();
    f16x8 af[4], bf[4];
    #pragma unroll
    for (int i = 0; i < 4; i++)
      af[i] = *(const f16x8*)(As + (wr * 64 + i * 16 + m_lo) * LDT + koff);
    #pragma unroll
    for (int j = 0; j < 4; j++)
      bf[j] = *(const f16x8*)(Bs + (wc * 64 + j * 16 + m_lo) * LDT + koff);
    #pragma unroll
    for (int i = 0; i < 4; i++)
      #pragma unroll
      for (int j = 0; j < 4; j++)
        acc[i][j] = __builtin_amdgcn_mfma_f32_16x16x32_f16(af[i], bf[j], acc[i][j], 0, 0, 0);
  }
  // C/D layout: col = lane&15, row = (lane>>4)*4 + reg
  #pragma unroll
  for (int i = 0; i < 4; i++)
    #pragma unroll
    for (int r = 0; r < 4; r++) {
      int grow = bm + wr * 64 + i * 16 + rq * 4 + r;
      if (grow < M)
        #pragma unroll
        for (int j = 0; j < 4; j++) {
          int gcol = bn + wc * 64 + j * 16 + m_lo;
          float v = acc[i][j][r];
          Cq[(size_t)grow * N + gcol] =
              (unsigned char)(__builtin_amdgcn_cvt_pk_fp8_f32(v, v, 0, false) & 0xFF);
        }
    }
}

// ========= fp16 MFMA GEMM, 128x64 tile (layer-2), OUTPUT = fp8 =============
__global__ __launch_bounds__(256) void gemm2_f16(const _Float16* __restrict__ A,
    const _Float16* __restrict__ Bt, unsigned char* __restrict__ Cq,
    int M, int N, int K) {
  __shared__ _Float16 As[128 * LDT];
  __shared__ _Float16 Bs[64 * LDT];
  const int bm = blockIdx.y * 128, bn = blockIdx.x * 64;
  const int tid = threadIdx.x;
  const int lane = tid & 63, wv = tid >> 6;
  const int ra = tid >> 1, sa = (tid & 1) * 16;  // A: 2 thr/row, 16 f16 each
  const int rb = tid >> 2, sb = (tid & 3) * 8;   // B: 4 thr/row, 8 f16 each
  const int m_lo = lane & 15, koff = (lane >> 4) * 8, rq = lane >> 4;
  f32x4 acc[2][4] = {};
  for (int k0 = 0; k0 < K; k0 += 32) {
    const int4 zero4 = {0, 0, 0, 0};
    int gra = bm + ra;
    int4 a0 = (gra < M) ? *(const int4*)(A + (size_t)gra * K + k0 + sa) : zero4;
    int4 a1 = (gra < M) ? *(const int4*)(A + (size_t)gra * K + k0 + sa + 8) : zero4;
    int4 b0 = *(const int4*)(Bt + (size_t)(bn + rb) * K + k0 + sb);
    __syncthreads();
    *(int4*)(As + ra * LDT + sa) = a0;
    *(int4*)(As + ra * LDT + sa + 8) = a1;
    *(int4*)(Bs + rb * LDT + sb) = b0;
    __syncthreads();
    f16x8 af[2], bf[4];
    #pragma unroll
    for (int i = 0; i < 2; i++)
      af[i] = *(const f16x8*)(As + (wv * 32 + i * 16 + m_lo) * LDT + koff);
    #pragma unroll
    for (int j = 0; j < 4; j++)
      bf[j] = *(const f16x8*)(Bs + (j * 16 + m_lo) * LDT + koff);
    #pragma unroll
    for (int i = 0; i < 2; i++)
      #pragma unroll
      for (int j = 0; j < 4; j++)
        acc[i][j] = __builtin_amdgcn_mfma_f32_16x16x32_f16(af[i], bf[j], acc[i][j], 0, 0, 0);
  }
  #pragma unroll
  for (int i = 0; i < 2; i++)
    #pragma unroll
    for (int r = 0; r < 4; r++) {
      int grow = bm + wv * 32 + i * 16 + rq * 4 + r;
      if (grow < M)
        #pragma unroll
        for (int j = 0; j < 4; j++) {
          int gcol = bn + j * 16 + m_lo;
          float v = acc[i][j][r];
          Cq[(size_t)grow * N + gcol] =
              (unsigned char)(__builtin_amdgcn_cvt_pk_fp8_f32(v, v, 0, false) & 0xFF);
        }
    }
}

// ====== layer-1 aggregation: one wave/node, fp8 gather, 16-WIDE UNROLL =====
// avg degree 17 -> most nodes finish in ONE batch of loads. Tail clamps to
// e1-1 (dup address = cache hit) with logit -16384 -> exp2 = 0 contribution.
__global__ __launch_bounds__(256) void agg1_kernel(
    const unsigned char* __restrict__ h1q, const float* __restrict__ a1s,
    const float* __restrict__ a1d, const int* __restrict__ offs,
    const int* __restrict__ csr, const float* __restrict__ b1,
    const float* __restrict__ wt2, _Float16* __restrict__ h1rb,
    float* __restrict__ a2s, float* __restrict__ a2d) {
  int wv = threadIdx.x >> 6, lane = threadIdx.x & 63;
  int n = blockIdx.x * 4 + wv;
  int c0 = lane * 8;
  int h = lane >> 4;                      // head for this lane's channels
  float ad_n = a1d[n * HEADS + h];
  int e0 = offs[n], e1 = offs[n + 1];     // degree >= 1 (self loop)
  float acc[8] = {};
  float den = 0.f;
  for (int e = e0; e < e1; e += 16) {
    int s[16]; float av[16]; uint2 q[16];
    #pragma unroll
    for (int j = 0; j < 16; j++) {
      int ee = e + j;
      s[j] = csr[(ee < e1) ? ee : e1 - 1];
    }
    #pragma unroll
    for (int j = 0; j < 16; j++) {
      av[j] = ((e + j) < e1) ? a1s[s[j] * HEADS + h] : -16384.f;
      q[j] = *(const uint2*)(h1q + (size_t)s[j] * (HEADS * HID) + c0);
    }
    #pragma unroll
    for (int j = 0; j < 16; j++) {
      float aa = av[j] + ad_n;
      aa = (aa > 0.f) ? aa : NEG_SLOPE * aa;
      float al = exp2f(aa);               // logits pre-scaled by LOG2E
      f32x2 p0 = __builtin_amdgcn_cvt_pk_f32_fp8(q[j].x, false);
      f32x2 p1 = __builtin_amdgcn_cvt_pk_f32_fp8(q[j].x, true);
      f32x2 p2 = __builtin_amdgcn_cvt_pk_f32_fp8(q[j].y, false);
      f32x2 p3 = __builtin_amdgcn_cvt_pk_f32_fp8(q[j].y, true);
      acc[0] += al * p0.x; acc[1] += al * p0.y;
      acc[2] += al * p1.x; acc[3] += al * p1.y;
      acc[4] += al * p2.x; acc[5] += al * p2.y;
      acc[6] += al * p3.x; acc[7] += al * p3.y;
      den += al;
    }
  }
  float inv = 1.f / den;
  f16x8 ov;
  float ps = 0.f, pd = 0.f;
  #pragma unroll
  for (int i = 0; i < 8; i++) {
    float o = fmaxf(acc[i] * inv + b1[c0 + i], 0.f);
    ov[i] = (_Float16)o;
    ps += o * wt2[c0 + i];
    pd += o * wt2[HEADS * HID + c0 + i];
  }
  *(f16x8*)(h1rb + (size_t)n * (HEADS * HID) + c0) = ov;
  #pragma unroll
  for (int o = 32; o > 0; o >>= 1) { ps += __shfl_down(ps, o); pd += __shfl_down(pd, o); }
  if (lane == 0) { a2s[n] = ps; a2d[n] = pd; }
}

// ==== layer-2 aggregation: one wave/node, fp8 gather, 16-WIDE UNROLL =======
__global__ __launch_bounds__(256) void agg2_kernel(
    const unsigned char* __restrict__ h2q, const float* __restrict__ a2s,
    const float* __restrict__ a2d, const int* __restrict__ offs,
    const int* __restrict__ csr, const float* __restrict__ b2,
    float* __restrict__ h2a) {
  int wv = threadIdx.x >> 6, lane = threadIdx.x & 63;
  int n = blockIdx.x * 4 + wv;
  int c = lane * 2;
  float ad_n = a2d[n];
  int e0 = offs[n], e1 = offs[n + 1];
  float acc0 = 0.f, acc1 = 0.f, den = 0.f;
  for (int e = e0; e < e1; e += 16) {
    int s[16]; float av[16]; unsigned short q[16];
    #pragma unroll
    for (int j = 0; j < 16; j++) {
      int ee = e + j;
      s[j] = csr[(ee < e1) ? ee : e1 - 1];
    }
    #pragma unroll
    for (int j = 0; j < 16; j++) {
      av[j] = ((e + j) < e1) ? a2s[s[j]] : -16384.f;
      q[j] = *(const unsigned short*)(h2q + (size_t)s[j] * HID + c);
    }
    #pragma unroll
    for (int j = 0; j < 16; j++) {
      float aa = av[j] + ad_n;
      aa = (aa > 0.f) ? aa : NEG_SLOPE * aa;
      float al = exp2f(aa);
      f32x2 p = __builtin_amdgcn_cvt_pk_f32_fp8((unsigned int)q[j], false);
      acc0 += al * p.x;
      acc1 += al * p.y;
      den += al;
    }
  }
  float inv = 1.f / den;
  *(float2*)&h2a[(size_t)n * HID + c] =
      make_float2(acc0 * inv + b2[c], acc1 * inv + b2[c + 1]);
}

// ====== fused mean-pool (contiguous node ranges) + 2-layer MLP head ========
__global__ __launch_bounds__(256) void pool_mlp(const float* __restrict__ h2a,
    const int* __restrict__ goff, const float* __restrict__ Wm1,
    const float* __restrict__ bm1, const float* __restrict__ Wm2,
    const float* __restrict__ bm2, float* __restrict__ outp) {
  __shared__ float part[2][HID];
  __shared__ float pl[HID];
  __shared__ float z[HID];
  int g = blockIdx.x, tid = threadIdx.x;
  int c = tid & 127, half = tid >> 7;
  int n0 = goff[g], n1 = goff[g + 1];
  float acc = 0.f;
  for (int n = n0 + half; n < n1; n += 2)
    acc += h2a[(size_t)n * HID + c];
  part[half][c] = acc;
  __syncthreads();
  if (tid < HID) {
    float inv = 1.f / fmaxf((float)(n1 - n0), 1.f);
    pl[tid] = (part[0][tid] + part[1][tid]) * inv;
  }
  __syncthreads();
  if (tid < HID) {
    float s = bm1[tid];
    for (int k = 0; k < HID; ++k) s += pl[k] * Wm1[k * HID + tid];
    z[tid] = fmaxf(s, 0.f);
  }
  __syncthreads();
  if (tid < OUT_CH) {
    float o = bm2[tid];
    for (int k = 0; k < HID; ++k) o += z[k] * Wm2[k * OUT_CH + tid];
    outp[g * OUT_CH + tid] = o;
  }
}

extern "C" void kernel_launch(void* const* d_in, const int* in_sizes, int n_in,
                              void* d_out, int out_size, void* d_ws, size_t ws_size,
                              hipStream_t stream) {
  const float* x    = (const float*)d_in[0];
  const int*   ei   = (const int*)d_in[1];
  const int*   batch= (const int*)d_in[2];
  const float* W1   = (const float*)d_in[3];
  const float* as1  = (const float*)d_in[4];
  const float* ad1  = (const float*)d_in[5];
  const float* b1   = (const float*)d_in[6];
  const float* W2   = (const float*)d_in[7];
  const float* as2  = (const float*)d_in[8];
  const float* ad2  = (const float*)d_in[9];
  const float* b2   = (const float*)d_in[10];
  const float* Wm1  = (const float*)d_in[11];
  const float* bm1  = (const float*)d_in[12];
  const float* Wm2  = (const float*)d_in[13];
  const float* bm2  = (const float*)d_in[14];
  float* outp = (float*)d_out;
  const int* srcp = ei;
  const int* dstp = ei + N_EDGES;

  // ---- workspace carve-up ----
  char* p = (char*)d_ws;
  auto alloc = [&](size_t bytes) {
    char* r = p; p += (bytes + 255) & ~(size_t)255; return r;
  };
  _Float16* xb   = (_Float16*)alloc((size_t)N_NODES * IN_CH * 2);
  unsigned char* h1q = (unsigned char*)alloc((size_t)N_NODES * HEADS * HID);  // fp8
  _Float16* h1rb = (_Float16*)alloc((size_t)N_NODES * HEADS * HID * 2);
  unsigned char* h2q = (unsigned char*)alloc((size_t)N_NODES * HID);          // fp8
  float*    h2a  = (float*)alloc((size_t)N_NODES * HID * 4);
  _Float16* W1T  = (_Float16*)alloc((size_t)(HEADS * HID) * IN_CH * 2);
  _Float16* W2T  = (_Float16*)alloc((size_t)HID * (HEADS * HID) * 2);
  float* wt1     = (float*)alloc(8 * IN_CH * 4);
  float* wt2     = (float*)alloc(2 * (HEADS * HID) * 4);
  float* a1s     = (float*)alloc((size_t)N_NODES * HEADS * 4);
  float* a1d     = (float*)alloc((size_t)N_NODES * HEADS * 4);
  float* a2s     = (float*)alloc((size_t)N_NODES * 4);
  float* a2d     = (float*)alloc((size_t)N_NODES * 4);
  int*   cnt     = (int*)alloc((size_t)N_NODES * 4);
  int*   offs    = (int*)alloc((size_t)(N_NODES + 1) * 4);
  int*   cursor  = (int*)alloc((size_t)N_NODES * 4);
  int*   csr     = (int*)alloc((size_t)ET * 4);
  int*   goff    = (int*)alloc((size_t)(N_GRAPHS + 1) * 4);

  hipMemsetAsync(cnt, 0, (size_t)N_NODES * 4, stream);

  // K1: weight prep + goff + edge histogram (independent pieces, one launch)
  prep_hist<<<(PH_TOTAL + 255) / 256, 256, 0, stream>>>(
      W1, W2, as1, ad1, as2, ad2, batch, dstp, cnt, W1T, W2T, wt1, wt2, goff);

  // K2: x->fp16 + layer-1 logits (blocks 0..4999) | exclusive scan (block 5000)
  conv_scan<<<SCB + 1, 256, 0, stream>>>(x, wt1, xb, a1s, a1d, cnt, offs, cursor);

  // K3: CSR fill (blocks 0..1328) | layer-1 GEMM -> fp8 (remaining 628 blocks)
  gemm1_fill<<<FILL_BLOCKS + G1_BN * G1_BM, 256, 0, stream>>>(
      xb, W1T, h1q, srcp, dstp, cursor, csr);

  agg1_kernel<<<N_NODES / 4, 256, 0, stream>>>(
      h1q, a1s, a1d, offs, csr, b1, wt2, h1rb, a2s, a2d);

  // layer 2: h2 = h1r @ W2 -> fp8  [20000,512]@[512,128]
  gemm2_f16<<<dim3(HID / 64, (N_NODES + 127) / 128), 256, 0, stream>>>(
      h1rb, W2T, h2q, N_NODES, HID, HEADS * HID);

  agg2_kernel<<<N_NODES / 4, 256, 0, stream>>>(h2q, a2s, a2d, offs, csr, b2, h2a);

  pool_mlp<<<N_GRAPHS, 256, 0, stream>>>(h2a, goff, Wm1, bm1, Wm2, bm2, outp);
}

// Round 11
// 248.570 us; speedup vs baseline: 1.0398x; 1.0398x over previous
//
#include <hip/hip_runtime.h>
#include <math.h>

#define N_NODES 20000
#define N_EDGES 320000
#define ET (N_EDGES + N_NODES)   // edges + self loops
#define IN_CH 256
#define HID 128
#define HEADS 4
#define OUT_CH 16
#define N_GRAPHS 128
#define NEG_SLOPE 0.2f
#define LOG2E 1.44269504f

typedef _Float16 f16x8 __attribute__((ext_vector_type(8)));
typedef _Float16 f16x4 __attribute__((ext_vector_type(4)));
typedef _Float16 f16x2 __attribute__((ext_vector_type(2)));
typedef float f32x4 __attribute__((ext_vector_type(4)));
typedef float f32x2 __attribute__((ext_vector_type(2)));

#define LDT 40   // padded LDS stride in f16 (80 B: 16B-aligned, 2-way max conflict)

// ========== K1: prep (W transpose, att folds, goff) + edge histogram ========
// cnt must be zeroed beforehand (hipMemsetAsync).
#define P1 (IN_CH * HEADS * HID)   // W1T
#define P2 (HEADS * HID * HID)     // W2T
#define P3 (8 * IN_CH)             // wt1 (pre-scaled by LOG2E)
#define P4 (HEADS * HID)           // wt2 (pre-scaled by LOG2E)
#define P5 (N_GRAPHS + 1)          // goff (binary search over sorted batch)
#define P6 ET                      // histogram by dst (incl self loops)
#define PH_TOTAL (P1 + P2 + P3 + P4 + P5 + P6)
__global__ void prep_hist(const float* __restrict__ W1, const float* __restrict__ W2,
    const float* __restrict__ as1, const float* __restrict__ ad1,
    const float* __restrict__ as2, const float* __restrict__ ad2,
    const int* __restrict__ batch, const int* __restrict__ dst,
    int* __restrict__ cnt,
    _Float16* __restrict__ W1T, _Float16* __restrict__ W2T,
    float* __restrict__ wt1, float* __restrict__ wt2, int* __restrict__ goff) {
  int idx = blockIdx.x * blockDim.x + threadIdx.x;
  if (idx < P1) {  // W1T[n*256+k] = W1[k*512+n]
    int n = idx >> 8, k = idx & 255;
    W1T[idx] = (_Float16)W1[(size_t)k * (HEADS * HID) + n];
    return;
  }
  idx -= P1;
  if (idx < P2) {  // W2T[n*512+k] = W2[k*128+n]
    int n = idx >> 9, k = idx & 511;
    W2T[idx] = (_Float16)W2[(size_t)k * HID + n];
    return;
  }
  idx -= P2;
  if (idx < P3) {  // wt1[j][i] = LOG2E * sum_c W1[i, h*128+c] * a{s,d}1[h][c]
    int j = idx >> 8, i = idx & 255;
    int sd = j >> 2, h = j & 3;
    const float* av = sd ? ad1 : as1;
    float s = 0.f;
    for (int c = 0; c < HID; ++c)
      s += W1[(size_t)i * (HEADS * HID) + h * HID + c] * av[h * HID + c];
    wt1[idx] = s * LOG2E;
    return;
  }
  idx -= P3;
  if (idx < P4) {  // wt2[0][c], wt2[1][c] (scaled by LOG2E)
    float s = 0.f, d = 0.f;
    for (int j = 0; j < HID; ++j) {
      float w = W2[(size_t)idx * HID + j];
      s += w * as2[j];
      d += w * ad2[j];
    }
    wt2[idx] = s * LOG2E;
    wt2[HEADS * HID + idx] = d * LOG2E;
    return;
  }
  idx -= P4;
  if (idx < P5) {  // batch sorted: goff[g] = lower_bound(batch, g)
    int g = idx;
    int lo = 0, hi = N_NODES;
    while (lo < hi) {
      int mid = (lo + hi) >> 1;
      if (batch[mid] < g) lo = mid + 1; else hi = mid;
    }
    goff[g] = lo;
    return;
  }
  idx -= P5;
  if (idx < P6) {  // histogram
    int d = (idx < N_EDGES) ? dst[idx] : (idx - N_EDGES);
    atomicAdd(&cnt[d], 1);
  }
}

// ===== K2: conv_x (blocks 0..4999) + exclusive scan (block 5000) ===========
// conv_x: x -> fp16 fused with a1s/a1d = x @ wt1 (wave per node).
// scan: 256 thr x 80 elems, VECTORIZED two-pass — int4 chunk loads keep the
// dependent chain ~5 deep (not 160); prefix math entirely in registers.
#define SCB 5000   // conv blocks; block SCB runs the scan
__global__ __launch_bounds__(256) void conv_scan(const float* __restrict__ x,
    const float* __restrict__ wt1, _Float16* __restrict__ xb,
    float* __restrict__ a1s, float* __restrict__ a1d,
    const int* __restrict__ cnt, int* __restrict__ offs, int* __restrict__ cursor) {
  __shared__ int wsum[4];
  if (blockIdx.x == SCB) {
    int tid = threadIdx.x;
    int base = tid * 80;                 // 256*80 = 20480; N_NODES = 250*80
    int s = 0;
    if (base < N_NODES) {                // threads 0..249 fully in-range
      #pragma unroll
      for (int ch = 0; ch < 5; ch++) {
        int4 v[4];
        #pragma unroll
        for (int u = 0; u < 4; u++)
          v[u] = *(const int4*)(cnt + base + ch * 16 + u * 4);
        #pragma unroll
        for (int u = 0; u < 4; u++)
          s += v[u].x + v[u].y + v[u].z + v[u].w;
      }
    }
    int lane = tid & 63, w = tid >> 6;
    int xv = s;
    #pragma unroll
    for (int o = 1; o < 64; o <<= 1) {
      int t = __shfl_up(xv, o);
      if (lane >= o) xv += t;
    }
    if (lane == 63) wsum[w] = xv;
    __syncthreads();
    int carry = 0;
    #pragma unroll
    for (int i = 0; i < 4; i++) carry += (i < w) ? wsum[i] : 0;
    int total = wsum[0] + wsum[1] + wsum[2] + wsum[3];
    int run = carry + xv - s;            // exclusive prefix for this thread
    if (base < N_NODES) {
      #pragma unroll
      for (int ch = 0; ch < 5; ch++) {
        int4 v[4];
        #pragma unroll
        for (int u = 0; u < 4; u++)
          v[u] = *(const int4*)(cnt + base + ch * 16 + u * 4);   // L1-hot
        #pragma unroll
        for (int u = 0; u < 4; u++) {
          int4 o4;
          o4.x = run; run += v[u].x;
          o4.y = run; run += v[u].y;
          o4.z = run; run += v[u].z;
          o4.w = run; run += v[u].w;
          *(int4*)(offs + base + ch * 16 + u * 4) = o4;
          *(int4*)(cursor + base + ch * 16 + u * 4) = o4;
        }
      }
    }
    if (tid == 0) offs[N_NODES] = total;
    return;
  }
  int node = blockIdx.x * 4 + (threadIdx.x >> 6);
  int lane = threadIdx.x & 63;
  if (node >= N_NODES) return;
  int c = lane * 4;
  float4 xv = *(const float4*)(x + (size_t)node * IN_CH + c);
  *(f16x4*)(xb + (size_t)node * IN_CH + c) =
      f16x4{(_Float16)xv.x, (_Float16)xv.y, (_Float16)xv.z, (_Float16)xv.w};
  float p[8];
  #pragma unroll
  for (int jj = 0; jj < 8; ++jj) {
    float4 w = *(const float4*)(wt1 + jj * IN_CH + c);
    p[jj] = xv.x * w.x + xv.y * w.y + xv.z * w.z + xv.w * w.w;
  }
  #pragma unroll
  for (int o = 32; o > 0; o >>= 1)
    #pragma unroll
    for (int jj = 0; jj < 8; ++jj) p[jj] += __shfl_down(p[jj], o);
  if (lane == 0) {
    #pragma unroll
    for (int h = 0; h < 4; ++h) {
      a1s[node * HEADS + h] = p[h];
      a1d[node * HEADS + h] = p[4 + h];
    }
  }
}

// ===== K3: CSR fill (blocks 0..1328) + layer-1 MFMA GEMM (fp8 out) =========
#define FILL_BLOCKS ((ET + 255) / 256)          // 1329
#define G1_BN ((HEADS * HID) / 128)             // 4
#define G1_BM ((N_NODES + 127) / 128)           // 157
__global__ __launch_bounds__(256) void gemm1_fill(const _Float16* __restrict__ A,
    const _Float16* __restrict__ Bt, unsigned char* __restrict__ Cq,
    const int* __restrict__ src, const int* __restrict__ dst,
    int* __restrict__ cursor, int* __restrict__ csr) {
  __shared__ _Float16 As[128 * LDT];
  __shared__ _Float16 Bs[128 * LDT];
  if (blockIdx.x < FILL_BLOCKS) {
    int e = blockIdx.x * 256 + threadIdx.x;
    if (e >= ET) return;
    int s, d;
    if (e < N_EDGES) { s = src[e]; d = dst[e]; } else { s = d = e - N_EDGES; }
    int pos = atomicAdd(&cursor[d], 1);
    csr[pos] = s;
    return;
  }
  const int g = blockIdx.x - FILL_BLOCKS;
  const int bm = (g >> 2) * 128, bn = (g & 3) * 128;
  const int M = N_NODES, N = HEADS * HID, K = IN_CH;
  const int tid = threadIdx.x;
  const int lane = tid & 63, wv = tid >> 6;
  const int wr = wv >> 1, wc = wv & 1;
  const int r0 = tid >> 2, seg = tid & 3;
  const int m_lo = lane & 15, koff = (lane >> 4) * 8, rq = lane >> 4;
  f32x4 acc[4][4] = {};
  for (int k0 = 0; k0 < K; k0 += 32) {
    const int4 zero4 = {0, 0, 0, 0};
    int gr0 = bm + r0, gr1 = bm + r0 + 64;
    int4 av0 = (gr0 < M) ? *(const int4*)(A + (size_t)gr0 * K + k0 + seg * 8) : zero4;
    int4 av1 = (gr1 < M) ? *(const int4*)(A + (size_t)gr1 * K + k0 + seg * 8) : zero4;
    int4 bv0 = *(const int4*)(Bt + (size_t)(bn + r0) * K + k0 + seg * 8);
    int4 bv1 = *(const int4*)(Bt + (size_t)(bn + r0 + 64) * K + k0 + seg * 8);
    __syncthreads();
    *(int4*)(As + r0 * LDT + seg * 8) = av0;
    *(int4*)(As + (r0 + 64) * LDT + seg * 8) = av1;
    *(int4*)(Bs + r0 * LDT + seg * 8) = bv0;
    *(int4*)(Bs + (r0 + 64) * LDT + seg * 8) = bv1;
    __syncthreads();
    f16x8 af[4], bf[4];
    #pragma unroll
    for (int i = 0; i < 4; i++)
      af[i] = *(const f16x8*)(As + (wr * 64 + i * 16 + m_lo) * LDT + koff);
    #pragma unroll
    for (int j = 0; j < 4; j++)
      bf[j] = *(const f16x8*)(Bs + (wc * 64 + j * 16 + m_lo) * LDT + koff);
    #pragma unroll
    for (int i = 0; i < 4; i++)
      #pragma unroll
      for (int j = 0; j < 4; j++)
        acc[i][j] = __builtin_amdgcn_mfma_f32_16x16x32_f16(af[i], bf[j], acc[i][j], 0, 0, 0);
  }
  // C/D layout: col = lane&15, row = (lane>>4)*4 + reg
  #pragma unroll
  for (int i = 0; i < 4; i++)
    #pragma unroll
    for (int r = 0; r < 4; r++) {
      int grow = bm + wr * 64 + i * 16 + rq * 4 + r;
      if (grow < M)
        #pragma unroll
        for (int j = 0; j < 4; j++) {
          int gcol = bn + wc * 64 + j * 16 + m_lo;
          float v = acc[i][j][r];
          Cq[(size_t)grow * N + gcol] =
              (unsigned char)(__builtin_amdgcn_cvt_pk_fp8_f32(v, v, 0, false) & 0xFF);
        }
    }
}

// ============== fp16 MFMA GEMM, 128x64 tile (layer-2, fp16 out) =============
__global__ __launch_bounds__(256) void gemm2_f16(const _Float16* __restrict__ A,
    const _Float16* __restrict__ Bt, _Float16* __restrict__ C,
    int M, int N, int K) {
  __shared__ _Float16 As[128 * LDT];
  __shared__ _Float16 Bs[64 * LDT];
  const int bm = blockIdx.y * 128, bn = blockIdx.x * 64;
  const int tid = threadIdx.x;
  const int lane = tid & 63, wv = tid >> 6;
  const int ra = tid >> 1, sa = (tid & 1) * 16;  // A: 2 thr/row, 16 f16 each
  const int rb = tid >> 2, sb = (tid & 3) * 8;   // B: 4 thr/row, 8 f16 each
  const int m_lo = lane & 15, koff = (lane >> 4) * 8, rq = lane >> 4;
  f32x4 acc[2][4] = {};
  for (int k0 = 0; k0 < K; k0 += 32) {
    const int4 zero4 = {0, 0, 0, 0};
    int gra = bm + ra;
    int4 a0 = (gra < M) ? *(const int4*)(A + (size_t)gra * K + k0 + sa) : zero4;
    int4 a1 = (gra < M) ? *(const int4*)(A + (size_t)gra * K + k0 + sa + 8) : zero4;
    int4 b0 = *(const int4*)(Bt + (size_t)(bn + rb) * K + k0 + sb);
    __syncthreads();
    *(int4*)(As + ra * LDT + sa) = a0;
    *(int4*)(As + ra * LDT + sa + 8) = a1;
    *(int4*)(Bs + rb * LDT + sb) = b0;
    __syncthreads();
    f16x8 af[2], bf[4];
    #pragma unroll
    for (int i = 0; i < 2; i++)
      af[i] = *(const f16x8*)(As + (wv * 32 + i * 16 + m_lo) * LDT + koff);
    #pragma unroll
    for (int j = 0; j < 4; j++)
      bf[j] = *(const f16x8*)(Bs + (j * 16 + m_lo) * LDT + koff);
    #pragma unroll
    for (int i = 0; i < 2; i++)
      #pragma unroll
      for (int j = 0; j < 4; j++)
        acc[i][j] = __builtin_amdgcn_mfma_f32_16x16x32_f16(af[i], bf[j], acc[i][j], 0, 0, 0);
  }
  #pragma unroll
  for (int i = 0; i < 2; i++)
    #pragma unroll
    for (int r = 0; r < 4; r++) {
      int grow = bm + wv * 32 + i * 16 + rq * 4 + r;
      if (grow < M)
        #pragma unroll
        for (int j = 0; j < 4; j++) {
          int gcol = bn + j * 16 + m_lo;
          C[(size_t)grow * N + gcol] = (_Float16)acc[i][j][r];
        }
    }
}

// ====== layer-1 aggregation: one wave/node, fp8 gather, 8-WIDE UNROLL ======
// 8 independent (csr -> logit,row) chains/iter at 28 VGPR -> full occupancy;
// the binding resource is outstanding-loads x resident-waves (R10 lesson:
// wider unroll raises VGPR and LOWERS the product).
__global__ __launch_bounds__(256) void agg1_kernel(
    const unsigned char* __restrict__ h1q, const float* __restrict__ a1s,
    const float* __restrict__ a1d, const int* __restrict__ offs,
    const int* __restrict__ csr, const float* __restrict__ b1,
    const float* __restrict__ wt2, _Float16* __restrict__ h1rb,
    float* __restrict__ a2s, float* __restrict__ a2d) {
  int wv = threadIdx.x >> 6, lane = threadIdx.x & 63;
  int n = blockIdx.x * 4 + wv;
  int c0 = lane * 8;
  int h = lane >> 4;                      // head for this lane's channels
  float ad_n = a1d[n * HEADS + h];
  int e0 = offs[n], e1 = offs[n + 1];     // degree >= 1 (self loop)
  float acc[8] = {};
  float den = 0.f;
  for (int e = e0; e < e1; e += 8) {
    int s[8]; float av[8]; uint2 q[8];
    #pragma unroll
    for (int j = 0; j < 8; j++) {
      int ee = e + j;
      s[j] = csr[(ee < e1) ? ee : e1 - 1];
    }
    #pragma unroll
    for (int j = 0; j < 8; j++) {
      av[j] = ((e + j) < e1) ? a1s[s[j] * HEADS + h] : -16384.f;
      q[j] = *(const uint2*)(h1q + (size_t)s[j] * (HEADS * HID) + c0);
    }
    #pragma unroll
    for (int j = 0; j < 8; j++) {
      float aa = av[j] + ad_n;
      aa = (aa > 0.f) ? aa : NEG_SLOPE * aa;
      float al = exp2f(aa);               // logits pre-scaled by LOG2E
      f32x2 p0 = __builtin_amdgcn_cvt_pk_f32_fp8(q[j].x, false);
      f32x2 p1 = __builtin_amdgcn_cvt_pk_f32_fp8(q[j].x, true);
      f32x2 p2 = __builtin_amdgcn_cvt_pk_f32_fp8(q[j].y, false);
      f32x2 p3 = __builtin_amdgcn_cvt_pk_f32_fp8(q[j].y, true);
      acc[0] += al * p0.x; acc[1] += al * p0.y;
      acc[2] += al * p1.x; acc[3] += al * p1.y;
      acc[4] += al * p2.x; acc[5] += al * p2.y;
      acc[6] += al * p3.x; acc[7] += al * p3.y;
      den += al;
    }
  }
  float inv = 1.f / den;
  f16x8 ov;
  float ps = 0.f, pd = 0.f;
  #pragma unroll
  for (int i = 0; i < 8; i++) {
    float o = fmaxf(acc[i] * inv + b1[c0 + i], 0.f);
    ov[i] = (_Float16)o;
    ps += o * wt2[c0 + i];
    pd += o * wt2[HEADS * HID + c0 + i];
  }
  *(f16x8*)(h1rb + (size_t)n * (HEADS * HID) + c0) = ov;
  #pragma unroll
  for (int o = 32; o > 0; o >>= 1) { ps += __shfl_down(ps, o); pd += __shfl_down(pd, o); }
  if (lane == 0) { a2s[n] = ps; a2d[n] = pd; }
}

// ==== layer-2 aggregation: one wave/node, fp16 gather, 8-WIDE UNROLL =======
__global__ __launch_bounds__(256) void agg2_kernel(
    const _Float16* __restrict__ h2b, const float* __restrict__ a2s,
    const float* __restrict__ a2d, const int* __restrict__ offs,
    const int* __restrict__ csr, const float* __restrict__ b2,
    float* __restrict__ h2a) {
  int wv = threadIdx.x >> 6, lane = threadIdx.x & 63;
  int n = blockIdx.x * 4 + wv;
  int c = lane * 2;
  float ad_n = a2d[n];
  int e0 = offs[n], e1 = offs[n + 1];
  float acc0 = 0.f, acc1 = 0.f, den = 0.f;
  for (int e = e0; e < e1; e += 8) {
    int s[8]; float av[8]; f16x2 q[8];
    #pragma unroll
    for (int j = 0; j < 8; j++) {
      int ee = e + j;
      s[j] = csr[(ee < e1) ? ee : e1 - 1];
    }
    #pragma unroll
    for (int j = 0; j < 8; j++) {
      av[j] = ((e + j) < e1) ? a2s[s[j]] : -16384.f;
      q[j] = *(const f16x2*)(h2b + (size_t)s[j] * HID + c);
    }
    #pragma unroll
    for (int j = 0; j < 8; j++) {
      float aa = av[j] + ad_n;
      aa = (aa > 0.f) ? aa : NEG_SLOPE * aa;
      float al = exp2f(aa);
      acc0 += al * (float)q[j].x;
      acc1 += al * (float)q[j].y;
      den += al;
    }
  }
  float inv = 1.f / den;
  *(float2*)&h2a[(size_t)n * HID + c] =
      make_float2(acc0 * inv + b2[c], acc1 * inv + b2[c + 1]);
}

// ====== fused mean-pool (contiguous node ranges) + 2-layer MLP head ========
__global__ __launch_bounds__(256) void pool_mlp(const float* __restrict__ h2a,
    const int* __restrict__ goff, const float* __restrict__ Wm1,
    const float* __restrict__ bm1, const float* __restrict__ Wm2,
    const float* __restrict__ bm2, float* __restrict__ outp) {
  __shared__ float part[2][HID];
  __shared__ float pl[HID];
  __shared__ float z[HID];
  int g = blockIdx.x, tid = threadIdx.x;
  int c = tid & 127, half = tid >> 7;
  int n0 = goff[g], n1 = goff[g + 1];
  float acc = 0.f;
  for (int n = n0 + half; n < n1; n += 2)
    acc += h2a[(size_t)n * HID + c];
  part[half][c] = acc;
  __syncthreads();
  if (tid < HID) {
    float inv = 1.f / fmaxf((float)(n1 - n0), 1.f);
    pl[tid] = (part[0][tid] + part[1][tid]) * inv;
  }
  __syncthreads();
  if (tid < HID) {
    float s = bm1[tid];
    for (int k = 0; k < HID; ++k) s += pl[k] * Wm1[k * HID + tid];
    z[tid] = fmaxf(s, 0.f);
  }
  __syncthreads();
  if (tid < OUT_CH) {
    float o = bm2[tid];
    for (int k = 0; k < HID; ++k) o += z[k] * Wm2[k * OUT_CH + tid];
    outp[g * OUT_CH + tid] = o;
  }
}

extern "C" void kernel_launch(void* const* d_in, const int* in_sizes, int n_in,
                              void* d_out, int out_size, void* d_ws, size_t ws_size,
                              hipStream_t stream) {
  const float* x    = (const float*)d_in[0];
  const int*   ei   = (const int*)d_in[1];
  const int*   batch= (const int*)d_in[2];
  const float* W1   = (const float*)d_in[3];
  const float* as1  = (const float*)d_in[4];
  const float* ad1  = (const float*)d_in[5];
  const float* b1   = (const float*)d_in[6];
  const float* W2   = (const float*)d_in[7];
  const float* as2  = (const float*)d_in[8];
  const float* ad2  = (const float*)d_in[9];
  const float* b2   = (const float*)d_in[10];
  const float* Wm1  = (const float*)d_in[11];
  const float* bm1  = (const float*)d_in[12];
  const float* Wm2  = (const float*)d_in[13];
  const float* bm2  = (const float*)d_in[14];
  float* outp = (float*)d_out;
  const int* srcp = ei;
  const int* dstp = ei + N_EDGES;

  // ---- workspace carve-up ----
  char* p = (char*)d_ws;
  auto alloc = [&](size_t bytes) {
    char* r = p; p += (bytes + 255) & ~(size_t)255; return r;
  };
  _Float16* xb   = (_Float16*)alloc((size_t)N_NODES * IN_CH * 2);
  unsigned char* h1q = (unsigned char*)alloc((size_t)N_NODES * HEADS * HID);  // fp8
  _Float16* h1rb = (_Float16*)alloc((size_t)N_NODES * HEADS * HID * 2);
  _Float16* h2b  = (_Float16*)alloc((size_t)N_NODES * HID * 2);
  float*    h2a  = (float*)alloc((size_t)N_NODES * HID * 4);
  _Float16* W1T  = (_Float16*)alloc((size_t)(HEADS * HID) * IN_CH * 2);
  _Float16* W2T  = (_Float16*)alloc((size_t)HID * (HEADS * HID) * 2);
  float* wt1     = (float*)alloc(8 * IN_CH * 4);
  float* wt2     = (float*)alloc(2 * (HEADS * HID) * 4);
  float* a1s     = (float*)alloc((size_t)N_NODES * HEADS * 4);
  float* a1d     = (float*)alloc((size_t)N_NODES * HEADS * 4);
  float* a2s     = (float*)alloc((size_t)N_NODES * 4);
  float* a2d     = (float*)alloc((size_t)N_NODES * 4);
  int*   cnt     = (int*)alloc((size_t)N_NODES * 4);
  int*   offs    = (int*)alloc((size_t)(N_NODES + 1) * 4);
  int*   cursor  = (int*)alloc((size_t)N_NODES * 4);
  int*   csr     = (int*)alloc((size_t)ET * 4);
  int*   goff    = (int*)alloc((size_t)(N_GRAPHS + 1) * 4);

  hipMemsetAsync(cnt, 0, (size_t)N_NODES * 4, stream);

  // K1: weight prep + goff + edge histogram (independent pieces, one launch)
  prep_hist<<<(PH_TOTAL + 255) / 256, 256, 0, stream>>>(
      W1, W2, as1, ad1, as2, ad2, batch, dstp, cnt, W1T, W2T, wt1, wt2, goff);

  // K2: x->fp16 + layer-1 logits (blocks 0..4999) | exclusive scan (block 5000)
  conv_scan<<<SCB + 1, 256, 0, stream>>>(x, wt1, xb, a1s, a1d, cnt, offs, cursor);

  // K3: CSR fill (blocks 0..1328) | layer-1 GEMM -> fp8 (remaining 628 blocks)
  gemm1_fill<<<FILL_BLOCKS + G1_BN * G1_BM, 256, 0, stream>>>(
      xb, W1T, h1q, srcp, dstp, cursor, csr);

  agg1_kernel<<<N_NODES / 4, 256, 0, stream>>>(
      h1q, a1s, a1d, offs, csr, b1, wt2, h1rb, a2s, a2d);

  // layer 2: h2 = h1r @ W2  [20000,512]@[512,128]
  gemm2_f16<<<dim3(HID / 64, (N_NODES + 127) / 128), 256, 0, stream>>>(
      h1rb, W2T, h2b, N_NODES, HID, HEADS * HID);

  agg2_kernel<<<N_NODES / 4, 256, 0, stream>>>(h2b, a2s, a2d, offs, csr, b2, h2a);

  pool_mlp<<<N_GRAPHS, 256, 0, stream>>>(h2a, goff, Wm1, bm1, Wm2, bm2, outp);
}